// Round 4
// baseline (172.282 us; speedup 1.0000x reference)
//
#include <hip/hip_runtime.h>
#include <math.h>

#define N_NODES 50000
#define N_EDGES 800000
#define IN_DIM 128
#define OUT_DIM 16
#define N_HEADS 4
#define HID 64            // N_HEADS*OUT_DIM
#define AW_COLS 33        // 2*OUT_DIM+1
#define GN 16             // nodes per block (gemm); LDS 40960
#define GEMM_BLK ((N_NODES + GN - 1) / GN)             // 3125 (exact: 3125*16=50000)
#define HTH 512           // R24: 512-thread blocks
#define HE 16             // edges per thread (hist)
#define HBLK ((N_EDGES + HTH * HE - 1) / (HTH * HE))   // 98
#define MAXDEG 64         // padded bucket width; deg~Poisson(16), max~35 (12 sigma margin)

// R24: occupancy via block shape. Counters (R21-R23): VALUBusy ~46% at
// Occupancy ~35% — ~30us of real f64 VALU work, ~35us stall at 4 waves/SIMD
// (LDS-capped: 40960 x 256-thread blocks -> 16 waves/CU = 50% of max).
// 512-thread blocks keep LDS/block at 40960 (4 blocks/CU = 2048 thr = HW max)
// but double residency: 8 waves/SIMD. Each wave-half computes 1 node (was 2);
// per-node W-convert cost +9% VALU traded for 2x latency hiding. Per-node
// accumulation order UNCHANGED -> h bit-identical.
// f64 GEMM is LOCKED: S~1.6e6 makes softmax near-one-hot; f32/bf16 h risks
// argmax flips vs the f32 jax reference -> O(1) output errors.
// NOTE (R7/R8): f64 MFMA produced zeros (wrong operand mapping) — shelved.
// NOTE (R10/R14): in-loop global reads for staging operands lose to bulk LDS
// staging; don't retry.
__global__ __launch_bounds__(512, 8) void gemm_hist(
    const float* __restrict__ nodes, const float* __restrict__ W,
    const float* __restrict__ b, const float* __restrict__ attn_W,
    const float* __restrict__ attn_b, const float* __restrict__ edges,
    float* __restrict__ h, double* __restrict__ z_src, double* __restrict__ z_dst,
    const int* __restrict__ senders, const int* __restrict__ receivers,
    int* __restrict__ counts, int* __restrict__ srt_padded,
    double* __restrict__ Ssum) {
    __shared__ float sW[HID * IN_DIM];     // 32 KB, rotated-quad layout
    __shared__ float sN[GN * IN_DIM];      // 8 KB (gemm staging / hist red[])
    int t = threadIdx.x;

    if (blockIdx.x < HBLK) {
        // ---------------- hist + direct bucket-scatter (R17) ----------------
        double* red = (double*)sN;         // 512 doubles = 4 KB, fits sN
        int base = blockIdx.x * HTH * HE + t;
        double sp = 0.0;
        #pragma unroll
        for (int j = 0; j < HE; ++j) {
            int e = base + j * HTH;
            if (e < N_EDGES) {
                int r = receivers[e];
                int rank = atomicAdd(&counts[r], 1);            // 0..deg-1
                if (rank < MAXDEG)
                    srt_padded[r * MAXDEG + rank] = senders[e];
                sp += (double)edges[senders[e]];
            }
        }
        red[t] = sp;
        __syncthreads();
        for (int off = 256; off > 0; off >>= 1) {
            if (t < off) red[t] += red[t + off];
            __syncthreads();
        }
        if (t == 0) atomicAdd(Ssum, red[0]);
    } else {
        // ------------- gemm body: 8 waves x 2 halves x 1 node -------------
        for (int i4 = t; i4 < HID * IN_DIM / 4; i4 += HTH) {   // 2048 quads / 512
            int o = i4 >> 5, kq = i4 & 31;
            float4 v = ((const float4*)W)[i4];
            *(float4*)&sW[o * IN_DIM + (((kq + o) & 31) << 2)] = v;
        }
        int node0 = (blockIdx.x - HBLK) * GN;
        for (int i4 = t; i4 < GN * IN_DIM / 4; i4 += HTH) {    // 512 quads / 512
            int ln = i4 >> 5;
            int n = node0 + ln;
            float4 v = (n < N_NODES) ? ((const float4*)nodes)[(long long)n * (IN_DIM / 4) + (i4 & 31)]
                                     : make_float4(0.f, 0.f, 0.f, 0.f);
            *(float4*)&sN[i4 << 2] = v;
        }
        __syncthreads();
        int w = t >> 6, l = t & 63;
        int half = l >> 5;                 // lane-half -> node
        int o2 = l & 31;                   // outputs o2 and o2+32
        int nw = w * 2 + half;             // local node index [0,16)
        double acc0, acc1;
        acc0 = (double)b[o2];
        acc1 = (double)b[o2 + 32];
        const float* wrow0 = &sW[o2 * IN_DIM];
        const float* wrow1 = &sW[(o2 + 32) * IN_DIM];
        const float* nbase = &sN[nw * IN_DIM];
        // software-pipelined kq loop: prefetch kq+1's quads before kq's FMAs
        int rot0 = (o2 & 31) << 2;
        float4 wv0 = *(const float4*)&wrow0[rot0];
        float4 wv1 = *(const float4*)&wrow1[rot0];
        float4 nva = *(const float4*)&nbase[0];
        for (int kq = 0; kq < 32; ++kq) {
            int kn = (kq + 1) & 31;                    // wraps harmlessly on last iter
            int rotn = ((kn + o2) & 31) << 2;
            float4 wv0n = *(const float4*)&wrow0[rotn];
            float4 wv1n = *(const float4*)&wrow1[rotn];
            float4 nvan = *(const float4*)&nbase[kn << 2];
            double w0x = (double)wv0.x, w0y = (double)wv0.y, w0z = (double)wv0.z, w0w = (double)wv0.w;
            double w1x = (double)wv1.x, w1y = (double)wv1.y, w1z = (double)wv1.z, w1w = (double)wv1.w;
            double nx = (double)nva.x, ny = (double)nva.y;
            double nz = (double)nva.z, nw_ = (double)nva.w;
            acc0 += w0x * nx; acc0 += w0y * ny;
            acc0 += w0z * nz; acc0 += w0w * nw_;
            acc1 += w1x * nx; acc1 += w1y * ny;
            acc1 += w1z * nz; acc1 += w1w * nw_;
            wv0 = wv0n; wv1 = wv1n; nva = nvan;
        }
        int hd0 = o2 >> 4, d = o2 & 15;    // heads: hd0 (out0), hd0+2 (out1)
        int hd1 = hd0 + 2;
        double aw00 = (double)attn_W[hd0 * AW_COLS + d];
        double aw01 = (double)attn_W[hd0 * AW_COLS + OUT_DIM + d];
        double aw10 = (double)attn_W[hd1 * AW_COLS + d];
        double aw11 = (double)attn_W[hd1 * AW_COLS + OUT_DIM + d];
        double wE0 = (double)attn_W[hd0 * AW_COLS + 2 * OUT_DIM];
        double wE1 = (double)attn_W[hd1 * AW_COLS + 2 * OUT_DIM];
        double bb0 = (double)attn_b[hd0], bb1 = (double)attn_b[hd1];
        {
            int n = node0 + nw;            // uniform per lane-half
            if (n < N_NODES) {
                float hf0 = (float)acc0;
                float hf1 = (float)acc1;
                h[(long long)n * HID + o2] = hf0;
                h[(long long)n * HID + o2 + 32] = hf1;
                double c00 = (double)hf0 * aw00;   // a_src part, head hd0
                double c01 = (double)hf0 * aw01;   // a_dst part, head hd0
                double c10 = (double)hf1 * aw10;   // a_src part, head hd1
                double c11 = (double)hf1 * aw11;   // a_dst part, head hd1
                #pragma unroll
                for (int k = 1; k <= 8; k <<= 1) {
                    c00 += __shfl_xor(c00, k, 64);
                    c01 += __shfl_xor(c01, k, 64);
                    c10 += __shfl_xor(c10, k, 64);
                    c11 += __shfl_xor(c11, k, 64);
                }
                if (d == 0) {
                    double se = (double)edges[n];
                    z_src[n * N_HEADS + hd0] = c00 + se * wE0;
                    z_dst[n * N_HEADS + hd0] = c01 + bb0;
                    z_src[n * N_HEADS + hd1] = c10 + se * wE1;
                    z_dst[n * N_HEADS + hd1] = c11 + bb1;
                }
            }
        }
    }
}

// R22 form (REVERTED from R23's dense loop — near-one-hot softmax means the
// ballot loop does ~1-2 gathers/node; dense did 16x the traffic, +12us).
// TWO nodes per wave, phases pairwise interleaved; launch_bounds(256,8).
// Numerics bit-exact lineage R21->R22.
__global__ __launch_bounds__(256, 8) void node_fused(
    const float* __restrict__ h, const double* __restrict__ z_src,
    const double* __restrict__ z_dst,
    const int* __restrict__ srt_padded, const int* __restrict__ counts,
    const double* __restrict__ Ssum, float* __restrict__ out) {
    int w = threadIdx.x >> 6;
    int lane = threadIdx.x & 63;
    int nA = blockIdx.x * 8 + w * 2;     // grid exact: 6250*8 = 50000
    int nB = nA + 1;
    int hd = lane >> 4, q = lane & 15;

    int degA = counts[nA]; if (degA > MAXDEG) degA = MAXDEG;
    int degB = counts[nB]; if (degB > MAXDEG) degB = MAXDEG;
    double S = 4.0 * Ssum[0];                       // sent_e tiled over heads
    double zdA = z_dst[nA * N_HEADS + hd];
    double zdB = z_dst[nB * N_HEADS + hd];

    // ---- edge-id gather (both nodes issued before use) ----
    int sA[4], sB[4];
    #pragma unroll
    for (int j = 0; j < 4; ++j) {
        int ei = q + 16 * j;
        sA[j] = (ei < degA) ? srt_padded[nA * MAXDEG + ei] : 0;
        sB[j] = (ei < degB) ? srt_padded[nB * MAXDEG + ei] : 0;
    }
    // ---- z_src scatter-gather + leaky (f64, then round) — bit-exact ----
    float yA[4], yB[4];
    #pragma unroll
    for (int j = 0; j < 4; ++j) {
        int ei = q + 16 * j;
        yA[j] = -INFINITY;
        yB[j] = -INFINITY;
        if (ei < degA) {
            double yy = z_src[sA[j] * N_HEADS + hd] + zdA;
            yy = yy > 0.0 ? yy : 0.01 * yy;
            yA[j] = (float)yy;
        }
        if (ei < degB) {
            double yy = z_src[sB[j] * N_HEADS + hd] + zdB;
            yy = yy > 0.0 ? yy : 0.01 * yy;
            yB[j] = (float)yy;
        }
    }
    // ---- per-head max: two butterfly chains interleaved ----
    float mA = fmaxf(fmaxf(yA[0], yA[1]), fmaxf(yA[2], yA[3]));
    float mB = fmaxf(fmaxf(yB[0], yB[1]), fmaxf(yB[2], yB[3]));
    #pragma unroll
    for (int k = 1; k <= 8; k <<= 1) {
        mA = fmaxf(mA, __shfl_xor(mA, k, 64));
        mB = fmaxf(mB, __shfl_xor(mB, k, 64));
    }
    // ---- exp + denominator (same expression order as R21) ----
    float evA[4], evB[4];
    float dA = 0.f, dB = 0.f;
    #pragma unroll
    for (int j = 0; j < 4; ++j) {
        evA[j] = (yA[j] == -INFINITY) ? 0.f
               : __expf((float)(S * ((double)yA[j] - (double)mA)));
        dA += evA[j];
        evB[j] = (yB[j] == -INFINITY) ? 0.f
               : __expf((float)(S * ((double)yB[j] - (double)mB)));
        dB += evB[j];
    }
    #pragma unroll
    for (int k = 1; k <= 8; k <<= 1) {
        dA += __shfl_xor(dA, k, 64);
        dB += __shfl_xor(dB, k, 64);
    }
    // ---- ballot-compressed accumulate, node A then node B (order preserved) ----
    float accA = 0.f;
    #pragma unroll
    for (int j = 0; j < 4; ++j) {
        unsigned long long mk = __ballot(evA[j] != 0.f);
        unsigned um = (unsigned)((mk | (mk >> 16) | (mk >> 32) | (mk >> 48)) & 0xFFFFull);
        while (um) {
            int qq = __builtin_ctz(um);
            um &= um - 1;
            int src = (lane & 48) | qq;                 // own head's copy
            float evv = __shfl(evA[j], src, 64);
            int sj = __shfl(sA[j], src, 64);
            if (evv != 0.f)
                accA = fmaf(evv, h[sj * HID + lane], accA);
        }
    }
    float accB = 0.f;
    #pragma unroll
    for (int j = 0; j < 4; ++j) {
        unsigned long long mk = __ballot(evB[j] != 0.f);
        unsigned um = (unsigned)((mk | (mk >> 16) | (mk >> 32) | (mk >> 48)) & 0xFFFFull);
        while (um) {
            int qq = __builtin_ctz(um);
            um &= um - 1;
            int src = (lane & 48) | qq;
            float evv = __shfl(evB[j], src, 64);
            int sj = __shfl(sB[j], src, 64);
            if (evv != 0.f)
                accB = fmaf(evv, h[sj * HID + lane], accB);
        }
    }
    float rA = (dA > 0.f) ? accA / dA : 0.f;
    float rB = (dB > 0.f) ? accB / dB : 0.f;
    out[nA * HID + lane] = rA > 0.f ? rA : 0.01f * rA;
    out[nB * HID + lane] = rB > 0.f ? rB : 0.01f * rB;
}

static inline char* ws_take(char*& p, size_t bytes) {
    char* cur = p;
    p += (bytes + 255) & ~(size_t)255;   // keep every buffer 256B-aligned
    return cur;
}

extern "C" void kernel_launch(void* const* d_in, const int* in_sizes, int n_in,
                              void* d_out, int out_size, void* d_ws, size_t ws_size,
                              hipStream_t stream) {
    const float* nodes     = (const float*)d_in[0];
    const float* edges     = (const float*)d_in[1];
    const int*   senders   = (const int*)d_in[2];
    const int*   receivers = (const int*)d_in[3];
    const float* W         = (const float*)d_in[4];
    const float* b         = (const float*)d_in[5];
    const float* attn_W    = (const float*)d_in[6];
    const float* attn_b    = (const float*)d_in[7];
    float* out = (float*)d_out;

    char* p = (char*)d_ws;
    float*  h          = (float*)ws_take(p, sizeof(float) * N_NODES * HID);
    double* z_src      = (double*)ws_take(p, sizeof(double) * N_NODES * N_HEADS);
    double* z_dst      = (double*)ws_take(p, sizeof(double) * N_NODES * N_HEADS);
    int*    counts     = (int*)ws_take(p, sizeof(int) * N_NODES);   // contiguous with
    char*   zpad       = ws_take(p, 256);                           // Ssum: one memset
    double* Ssum       = (double*)zpad;
    int*    srt_padded = (int*)ws_take(p, sizeof(int) * (size_t)N_NODES * MAXDEG);

    // counts (256B-rounded) + the Ssum pad in one memset; srt_padded needs no init
    hipMemsetAsync(counts, 0, ((sizeof(int) * N_NODES + 255) & ~(size_t)255) + 256, stream);

    gemm_hist<<<HBLK + GEMM_BLK, HTH, 0, stream>>>(
        nodes, W, b, attn_W, attn_b, edges, h, z_src, z_dst,
        senders, receivers, counts, srt_padded, Ssum);
    node_fused<<<(N_NODES + 7) / 8, 256, 0, stream>>>(
        h, z_src, z_dst, srt_padded, counts, Ssum, out);
}

// Round 5
// 155.108 us; speedup vs baseline: 1.1107x; 1.1107x over previous
//
#include <hip/hip_runtime.h>
#include <math.h>

#define N_NODES 50000
#define N_EDGES 800000
#define IN_DIM 128
#define OUT_DIM 16
#define N_HEADS 4
#define HID 64            // N_HEADS*OUT_DIM
#define AW_COLS 33        // 2*OUT_DIM+1
#define GN 16             // nodes per block (gemm); 3125*16 = 50000 exact
#define GEMM_BLK ((N_NODES + GN - 1) / GN)             // 3125
#define HE 16             // edges per thread (hist)
#define HBLK ((N_EDGES + 256 * HE - 1) / (256 * HE))   // 196
#define MAXDEG 64         // padded bucket width; deg~Poisson(16), max~35 (12 sigma margin)

// R25: cut DS traffic per node at unchanged occupancy. R24 proved the kernel
// is DS+VALU co-bound (occupancy 35->57% made it SLOWER because DS/node rose
// 1.5x). Lane-tile algebra: r out x c nodes costs (r+c) DS instrs/kq for
// r*G x c*H coverage; optimum at c=4,H=4 (r=4): 8 instrs cover 16 nodes x 64
// outs = 0.5 instr/node (R21: 1.0). One wave covers the whole GN=16 tile, so
// the 4 waves SPLIT K 4-ways (8 kq each) + f64 LDS reduction (scratch overlays
// sW post-barrier; 17-double row pad -> 2-way banks max). Converts halve too
// (32 cvt per 64 FMA). LDS stays 40960 -> 4 blocks/CU. Numerics: f64 products
// exact; 4-way k-reorder perturbs h by ~1e-16 (harmless vs 1e-7 f32-ref gap);
// z-epilogue shuffle order verbatim from R21.
// f64 GEMM LOCKED (near-one-hot softmax, argmax flips vs f32 ref).
// NOTE (R7/R8): f64 MFMA produced zeros — shelved.
// NOTE (R10/R14): in-loop global reads lose to bulk LDS staging; don't retry.
// NOTE (R24): more waves without less traffic regresses; don't retry.
__global__ __launch_bounds__(256, 4) void gemm_hist(
    const float* __restrict__ nodes, const float* __restrict__ W,
    const float* __restrict__ b, const float* __restrict__ attn_W,
    const float* __restrict__ attn_b, const float* __restrict__ edges,
    float* __restrict__ h, double* __restrict__ z_src, double* __restrict__ z_dst,
    const int* __restrict__ senders, const int* __restrict__ receivers,
    int* __restrict__ counts, int* __restrict__ srt_padded,
    double* __restrict__ Ssum) {
    __shared__ float sW[HID * IN_DIM];     // 32 KB; reused as f64 scratch after barrier2
    __shared__ float sN[GN * IN_DIM];      // 8 KB; reused as h_lds after barrier2
    int t = threadIdx.x;

    if (blockIdx.x < HBLK) {
        // ---------------- hist + direct bucket-scatter (R17) ----------------
        double* red = (double*)sN;
        int base = blockIdx.x * 256 * HE + t;
        double sp = 0.0;
        #pragma unroll
        for (int j = 0; j < HE; ++j) {
            int e = base + j * 256;
            if (e < N_EDGES) {
                int r = receivers[e];
                int rank = atomicAdd(&counts[r], 1);            // 0..deg-1
                if (rank < MAXDEG)
                    srt_padded[r * MAXDEG + rank] = senders[e];
                sp += (double)edges[senders[e]];
            }
        }
        red[t] = sp;
        __syncthreads();
        for (int off = 128; off > 0; off >>= 1) {
            if (t < off) red[t] += red[t + off];
            __syncthreads();
        }
        if (t == 0) atomicAdd(Ssum, red[0]);
    } else {
        // -------- gemm body: 4x4 lane tile, 4-way k-split, GN=16 --------
        for (int i4 = t; i4 < HID * IN_DIM / 4; i4 += 256) {   // 2048 quads
            int o = i4 >> 5, kq = i4 & 31;
            float4 v = ((const float4*)W)[i4];
            *(float4*)&sW[o * IN_DIM + (((kq + o) & 31) << 2)] = v;
        }
        int node0 = (blockIdx.x - HBLK) * GN;
        for (int i4 = t; i4 < GN * IN_DIM / 4; i4 += 256) {    // 512 quads, rotated
            int ln = i4 >> 5, kq = i4 & 31;
            float4 v = ((const float4*)nodes)[(long long)(node0 + ln) * (IN_DIM / 4) + kq];
            *(float4*)&sN[ln * IN_DIM + (((kq + ln) & 31) << 2)] = v;
        }
        __syncthreads();                   // barrier 1

        int w = t >> 6, l = t & 63;
        int og = l & 15;                   // outputs og + 16j, j=0..3
        int ng = l >> 4;                   // nodes   ng + 4i,  i=0..3
        int kbase = w * 8;                 // this wave's kq range [kbase, kbase+8)

        double acc[4][4];                  // [j][i]
        #pragma unroll
        for (int j = 0; j < 4; ++j)
            #pragma unroll
            for (int i = 0; i < 4; ++i) acc[j][i] = 0.0;

        #pragma unroll
        for (int s = 0; s < 8; ++s) {
            int kq = kbase + s;
            float4 wq[4], xq[4];
            #pragma unroll
            for (int j = 0; j < 4; ++j) {
                int o = og + 16 * j;
                wq[j] = *(const float4*)&sW[o * IN_DIM + (((kq + o) & 31) << 2)];
            }
            #pragma unroll
            for (int i = 0; i < 4; ++i) {
                int n = ng + 4 * i;
                xq[i] = *(const float4*)&sN[n * IN_DIM + (((kq + n) & 31) << 2)];
            }
            #pragma unroll
            for (int j = 0; j < 4; ++j) {
                double wx = (double)wq[j].x, wy = (double)wq[j].y;
                double wz = (double)wq[j].z, ww = (double)wq[j].w;
                #pragma unroll
                for (int i = 0; i < 4; ++i) {
                    double nx = (double)xq[i].x, ny = (double)xq[i].y;
                    double nz = (double)xq[i].z, nw = (double)xq[i].w;
                    acc[j][i] += wx * nx; acc[j][i] += wy * ny;
                    acc[j][i] += wz * nz; acc[j][i] += ww * nw;
                }
            }
        }
        __syncthreads();                   // barrier 2: sW/sN reads done

        // ---- k-reduction: waves 1-3 dump partials, wave 0 sums ----
        double* scr = (double*)sW;         // 3 * 64 * 17 doubles = 26112 B <= 32 KB
        if (w > 0) {
            double* dst = &scr[((w - 1) * 64 + l) * 17];
            #pragma unroll
            for (int j = 0; j < 4; ++j)
                #pragma unroll
                for (int i = 0; i < 4; ++i) dst[j * 4 + i] = acc[j][i];
        }
        __syncthreads();                   // barrier 3
        float* h_lds = (float*)sN;         // 16 * 64 * 4 = 4096 B
        if (w == 0) {
            #pragma unroll
            for (int j = 0; j < 4; ++j) {
                double bj = (double)b[og + 16 * j];
                #pragma unroll
                for (int i = 0; i < 4; ++i) {
                    double sum = bj + acc[j][i];
                    sum += scr[(0 * 64 + l) * 17 + j * 4 + i];
                    sum += scr[(1 * 64 + l) * 17 + j * 4 + i];
                    sum += scr[(2 * 64 + l) * 17 + j * 4 + i];
                    h_lds[(ng + 4 * i) * HID + og + 16 * j] = (float)sum;
                }
            }
        }
        __syncthreads();                   // barrier 4

        // ---- epilogue: R21 layout/order verbatim, h values from h_lds ----
        int half = l >> 5;
        int o2 = l & 31;
        int nwbase = w * 4 + half * 2;
        int hd0 = o2 >> 4, d = o2 & 15;
        int hd1 = hd0 + 2;
        double aw00 = (double)attn_W[hd0 * AW_COLS + d];
        double aw01 = (double)attn_W[hd0 * AW_COLS + OUT_DIM + d];
        double aw10 = (double)attn_W[hd1 * AW_COLS + d];
        double aw11 = (double)attn_W[hd1 * AW_COLS + OUT_DIM + d];
        double wE0 = (double)attn_W[hd0 * AW_COLS + 2 * OUT_DIM];
        double wE1 = (double)attn_W[hd1 * AW_COLS + 2 * OUT_DIM];
        double bb0 = (double)attn_b[hd0], bb1 = (double)attn_b[hd1];
        #pragma unroll
        for (int j = 0; j < 2; ++j) {
            int nl = nwbase + j;
            int n = node0 + nl;            // always < 50000 (exact tiling)
            float hf0 = h_lds[nl * HID + o2];
            float hf1 = h_lds[nl * HID + o2 + 32];
            double c00 = (double)hf0 * aw00;   // a_src part, head hd0
            double c01 = (double)hf0 * aw01;   // a_dst part, head hd0
            double c10 = (double)hf1 * aw10;   // a_src part, head hd1
            double c11 = (double)hf1 * aw11;   // a_dst part, head hd1
            #pragma unroll
            for (int k = 1; k <= 8; k <<= 1) {
                c00 += __shfl_xor(c00, k, 64);
                c01 += __shfl_xor(c01, k, 64);
                c10 += __shfl_xor(c10, k, 64);
                c11 += __shfl_xor(c11, k, 64);
            }
            if (d == 0) {
                double se = (double)edges[n];
                z_src[n * N_HEADS + hd0] = c00 + se * wE0;
                z_dst[n * N_HEADS + hd0] = c01 + bb0;
                z_src[n * N_HEADS + hd1] = c10 + se * wE1;
                z_dst[n * N_HEADS + hd1] = c11 + bb1;
            }
        }
        // coalesced h write: block's h region is contiguous (1024 floats)
        ((float4*)h)[(long long)node0 * (HID / 4) + t] = ((const float4*)h_lds)[t];
    }
}

// R22 form (best known). TWO nodes per wave, phases pairwise interleaved;
// near-one-hot softmax -> ballot loop does ~1-4 gathers/node (R23's dense
// rewrite did 16x traffic, +12us — don't retry). launch_bounds(256,8).
__global__ __launch_bounds__(256, 8) void node_fused(
    const float* __restrict__ h, const double* __restrict__ z_src,
    const double* __restrict__ z_dst,
    const int* __restrict__ srt_padded, const int* __restrict__ counts,
    const double* __restrict__ Ssum, float* __restrict__ out) {
    int w = threadIdx.x >> 6;
    int lane = threadIdx.x & 63;
    int nA = blockIdx.x * 8 + w * 2;     // grid exact: 6250*8 = 50000
    int nB = nA + 1;
    int hd = lane >> 4, q = lane & 15;

    int degA = counts[nA]; if (degA > MAXDEG) degA = MAXDEG;
    int degB = counts[nB]; if (degB > MAXDEG) degB = MAXDEG;
    double S = 4.0 * Ssum[0];                       // sent_e tiled over heads
    double zdA = z_dst[nA * N_HEADS + hd];
    double zdB = z_dst[nB * N_HEADS + hd];

    // ---- edge-id gather (both nodes issued before use) ----
    int sA[4], sB[4];
    #pragma unroll
    for (int j = 0; j < 4; ++j) {
        int ei = q + 16 * j;
        sA[j] = (ei < degA) ? srt_padded[nA * MAXDEG + ei] : 0;
        sB[j] = (ei < degB) ? srt_padded[nB * MAXDEG + ei] : 0;
    }
    // ---- z_src scatter-gather + leaky (f64, then round) — bit-exact ----
    float yA[4], yB[4];
    #pragma unroll
    for (int j = 0; j < 4; ++j) {
        int ei = q + 16 * j;
        yA[j] = -INFINITY;
        yB[j] = -INFINITY;
        if (ei < degA) {
            double yy = z_src[sA[j] * N_HEADS + hd] + zdA;
            yy = yy > 0.0 ? yy : 0.01 * yy;
            yA[j] = (float)yy;
        }
        if (ei < degB) {
            double yy = z_src[sB[j] * N_HEADS + hd] + zdB;
            yy = yy > 0.0 ? yy : 0.01 * yy;
            yB[j] = (float)yy;
        }
    }
    // ---- per-head max: two butterfly chains interleaved ----
    float mA = fmaxf(fmaxf(yA[0], yA[1]), fmaxf(yA[2], yA[3]));
    float mB = fmaxf(fmaxf(yB[0], yB[1]), fmaxf(yB[2], yB[3]));
    #pragma unroll
    for (int k = 1; k <= 8; k <<= 1) {
        mA = fmaxf(mA, __shfl_xor(mA, k, 64));
        mB = fmaxf(mB, __shfl_xor(mB, k, 64));
    }
    // ---- exp + denominator (same expression order as R21) ----
    float evA[4], evB[4];
    float dA = 0.f, dB = 0.f;
    #pragma unroll
    for (int j = 0; j < 4; ++j) {
        evA[j] = (yA[j] == -INFINITY) ? 0.f
               : __expf((float)(S * ((double)yA[j] - (double)mA)));
        dA += evA[j];
        evB[j] = (yB[j] == -INFINITY) ? 0.f
               : __expf((float)(S * ((double)yB[j] - (double)mB)));
        dB += evB[j];
    }
    #pragma unroll
    for (int k = 1; k <= 8; k <<= 1) {
        dA += __shfl_xor(dA, k, 64);
        dB += __shfl_xor(dB, k, 64);
    }
    // ---- ballot-compressed accumulate, node A then node B (order preserved) ----
    float accA = 0.f;
    #pragma unroll
    for (int j = 0; j < 4; ++j) {
        unsigned long long mk = __ballot(evA[j] != 0.f);
        unsigned um = (unsigned)((mk | (mk >> 16) | (mk >> 32) | (mk >> 48)) & 0xFFFFull);
        while (um) {
            int qq = __builtin_ctz(um);
            um &= um - 1;
            int src = (lane & 48) | qq;                 // own head's copy
            float evv = __shfl(evA[j], src, 64);
            int sj = __shfl(sA[j], src, 64);
            if (evv != 0.f)
                accA = fmaf(evv, h[sj * HID + lane], accA);
        }
    }
    float accB = 0.f;
    #pragma unroll
    for (int j = 0; j < 4; ++j) {
        unsigned long long mk = __ballot(evB[j] != 0.f);
        unsigned um = (unsigned)((mk | (mk >> 16) | (mk >> 32) | (mk >> 48)) & 0xFFFFull);
        while (um) {
            int qq = __builtin_ctz(um);
            um &= um - 1;
            int src = (lane & 48) | qq;
            float evv = __shfl(evB[j], src, 64);
            int sj = __shfl(sB[j], src, 64);
            if (evv != 0.f)
                accB = fmaf(evv, h[sj * HID + lane], accB);
        }
    }
    float rA = (dA > 0.f) ? accA / dA : 0.f;
    float rB = (dB > 0.f) ? accB / dB : 0.f;
    out[nA * HID + lane] = rA > 0.f ? rA : 0.01f * rA;
    out[nB * HID + lane] = rB > 0.f ? rB : 0.01f * rB;
}

static inline char* ws_take(char*& p, size_t bytes) {
    char* cur = p;
    p += (bytes + 255) & ~(size_t)255;   // keep every buffer 256B-aligned
    return cur;
}

extern "C" void kernel_launch(void* const* d_in, const int* in_sizes, int n_in,
                              void* d_out, int out_size, void* d_ws, size_t ws_size,
                              hipStream_t stream) {
    const float* nodes     = (const float*)d_in[0];
    const float* edges     = (const float*)d_in[1];
    const int*   senders   = (const int*)d_in[2];
    const int*   receivers = (const int*)d_in[3];
    const float* W         = (const float*)d_in[4];
    const float* b         = (const float*)d_in[5];
    const float* attn_W    = (const float*)d_in[6];
    const float* attn_b    = (const float*)d_in[7];
    float* out = (float*)d_out;

    char* p = (char*)d_ws;
    float*  h          = (float*)ws_take(p, sizeof(float) * N_NODES * HID);
    double* z_src      = (double*)ws_take(p, sizeof(double) * N_NODES * N_HEADS);
    double* z_dst      = (double*)ws_take(p, sizeof(double) * N_NODES * N_HEADS);
    int*    counts     = (int*)ws_take(p, sizeof(int) * N_NODES);   // contiguous with
    char*   zpad       = ws_take(p, 256);                           // Ssum: one memset
    double* Ssum       = (double*)zpad;
    int*    srt_padded = (int*)ws_take(p, sizeof(int) * (size_t)N_NODES * MAXDEG);

    // counts (256B-rounded) + the Ssum pad in one memset; srt_padded needs no init
    hipMemsetAsync(counts, 0, ((sizeof(int) * N_NODES + 255) & ~(size_t)255) + 256, stream);

    gemm_hist<<<HBLK + GEMM_BLK, 256, 0, stream>>>(
        nodes, W, b, attn_W, attn_b, edges, h, z_src, z_dst,
        senders, receivers, counts, srt_padded, Ssum);
    node_fused<<<(N_NODES + 7) / 8, 256, 0, stream>>>(
        h, z_src, z_dst, srt_padded, counts, Ssum, out);
}